// Round 17
// baseline (522.258 us; speedup 1.0000x reference)
//
#include <hip/hip_runtime.h>

#define T_SEQ 188
#define NB    256
#define NIN   128
#define NH    256
#define SCQ   (0.0625f / 16129.0f)   // (0.0625/127) * (1/127)
#define NREC  128                    // rec WGs; gemm WGs follow

typedef __attribute__((ext_vector_type(8))) short s16x8;
typedef __attribute__((ext_vector_type(4))) short s16x4;
typedef __attribute__((ext_vector_type(4))) float f32x4;
typedef __attribute__((ext_vector_type(4))) int   i32x4;

__device__ __forceinline__ short f2bf(float f) {
    union { float f; unsigned u; } v; v.f = f;
    unsigned r = v.u + 0x7fffu + ((v.u >> 16) & 1u);   // RNE
    return (short)(r >> 16);
}
__device__ __forceinline__ float bf2f(unsigned short s) {
    union { unsigned u; float f; } t; t.u = ((unsigned)s) << 16; return t.f;
}
__device__ __forceinline__ float sigf(float x) {
    return __builtin_amdgcn_rcpf(1.0f + __expf(-x));
}
__device__ __forceinline__ float tanh_(float x) {
    return 1.0f - 2.0f * __builtin_amdgcn_rcpf(__expf(2.0f * x) + 1.0f);
}
__device__ __forceinline__ void lds_barrier() {
    asm volatile("s_waitcnt lgkmcnt(0)" ::: "memory");
    __builtin_amdgcn_s_barrier();
    asm volatile("" ::: "memory");
}

// ---- rec step (R13-proven inner loop, untouched logic) ----
__device__ __forceinline__ void lstm_step(
    int p, int w, int l, int lg, int lb, int c, int huq, int hwb,
    const unsigned short*& xpp, long dxp, float*& outp, long dout,
    int* hl, int (*rscr)[4][4][16],
    const i32x4 (&wq)[4][4], float& cst,
    unsigned short (&cur)[4], unsigned short (&nxt)[4])
{
    #pragma unroll
    for (int G = 0; G < 4; ++G)
        nxt[G] = xpp[G * 256];
    xpp += dxp;

    i32x4 ac[4];
    #pragma unroll
    for (int G = 0; G < 4; ++G) {
        ac[G][0] = 0; ac[G][1] = 0; ac[G][2] = 0; ac[G][3] = 0;
    }
    #pragma unroll
    for (int kk = 0; kk < 4; ++kk) {
        i32x4 bq = *(const i32x4*)&hl[p * 1024 + kk * 256 + 4 * l];
        ac[0] = __builtin_amdgcn_mfma_i32_16x16x64_i8(wq[0][kk], bq, ac[0], 0, 0, 0);
        ac[1] = __builtin_amdgcn_mfma_i32_16x16x64_i8(wq[1][kk], bq, ac[1], 0, 0, 0);
        ac[2] = __builtin_amdgcn_mfma_i32_16x16x64_i8(wq[2][kk], bq, ac[2], 0, 0, 0);
        ac[3] = __builtin_amdgcn_mfma_i32_16x16x64_i8(wq[3][kk], bq, ac[3], 0, 0, 0);
    }

    if (lb < 4) {
        #pragma unroll
        for (int G = 0; G < 4; ++G)
            *(i32x4*)&rscr[w][G][lb][4 * lg] = ac[G];
    }
    asm volatile("s_waitcnt lgkmcnt(0)" ::: "memory");
    int av[4];
    #pragma unroll
    for (int G = 0; G < 4; ++G)
        av[G] = rscr[w][G][c][huq];
    asm volatile("s_waitcnt lgkmcnt(0)" ::: "memory");

    const float gi = SCQ * (float)av[0] + bf2f(cur[0]);
    const float gf = SCQ * (float)av[1] + bf2f(cur[1]);
    const float gg = SCQ * (float)av[2] + bf2f(cur[2]);
    const float go = SCQ * (float)av[3] + bf2f(cur[3]);
    const float iv = sigf(gi), fv = sigf(gf);
    const float gv = tanh_(gg), ov = sigf(go);
    const float cc = fv * cst + iv * gv;
    cst = cc;
    const float h = ov * tanh_(cc);
    *outp = h;
    outp += dout;
    ((signed char*)hl)[(p ^ 1) * 4096 + hwb] = (signed char)(int)rintf(h * 127.0f);

    lds_barrier();
}

// ======================= fused producer/consumer kernel ==========================
// bid < NREC: recurrence (R13 structure) + per-32-step flag chunk-wait.
// bid >= NREC: xp gemm tile (t,64 rows,d, all N). Produces in consumer t-order.
//   Publish: sc0sc1 coalesced stores (IC) -> __syncthreads (vmcnt drain) ->
//   tid0 sc0sc1 flag store. One-directional; deadlock-free by capacity.
__global__ __launch_bounds__(1024, 4) void lstm_fused(
    const float* __restrict__ x,
    const float* __restrict__ w_ih_f, const float* __restrict__ w_hh_f,
    const float* __restrict__ b_ih_f, const float* __restrict__ b_hh_f,
    const float* __restrict__ w_ih_b, const float* __restrict__ w_hh_b,
    const float* __restrict__ b_ih_b, const float* __restrict__ b_hh_b,
    unsigned short* __restrict__ xp, int* __restrict__ flags,
    float* __restrict__ out)
{
    __shared__ char smem[30208];
    const int bid = blockIdx.x;
    const int tid = threadIdx.x;

    if (bid >= NREC) {
        // ================= gemm role =================
        const int gid = bid - NREC;
        const int d   = gid & 1;
        const int mt  = gid >> 1;
        const int tseq = mt >> 2, g = mt & 3;
        const int t   = d ? (T_SEQ - 1 - tseq) : tseq;   // consumer order
        const int b0  = g * 64;
        const float* w_ih = d ? w_ih_b : w_ih_f;
        const float* b_ih = d ? b_ih_b : b_ih_f;
        const float* b_hh = d ? b_hh_b : b_hh_f;

        if (tid >= 256) {   // idle waves: match active barrier count, then exit
            for (int i = 0; i < 33; ++i) __syncthreads();
            return;
        }

        short (*wl)[136]  = (short(*)[136])smem;            // 17408 B
        short (*xo)[68]   = (short(*)[68])(smem + 17408);   //  8704 B
        float* biasS      = (float*)(smem + 26112);         //  4096 B

        const int v = tid >> 6, l = tid & 63, lg = l >> 4, lb = l & 15;
        {
            const int gg4 = tid * 4;
            float4 bi = *(const float4*)(b_ih + gg4);
            float4 bh = *(const float4*)(b_hh + gg4);
            biasS[gg4 + 0] = bi.x + bh.x; biasS[gg4 + 1] = bi.y + bh.y;
            biasS[gg4 + 2] = bi.z + bh.z; biasS[gg4 + 3] = bi.w + bh.w;
        }
        // x A-fragments -> registers (once)
        s16x8 a[4];
        {
            const float* xr = x + ((size_t)(t * NB + b0 + 16 * v + lb)) * NIN + 8 * lg;
            #pragma unroll
            for (int kk = 0; kk < 4; ++kk) {
                float4 p0 = *(const float4*)(xr + 32 * kk);
                float4 p1 = *(const float4*)(xr + 32 * kk + 4);
                s16x8 tv;
                tv[0] = f2bf(p0.x); tv[1] = f2bf(p0.y); tv[2] = f2bf(p0.z); tv[3] = f2bf(p0.w);
                tv[4] = f2bf(p1.x); tv[5] = f2bf(p1.y); tv[6] = f2bf(p1.z); tv[7] = f2bf(p1.w);
                a[kk] = tv;
            }
        }
        const int wr = tid >> 2, wk = (tid & 3) * 32;
        const int orow = tid >> 2, oko = (tid & 3) * 16;

        for (int nt = 0; nt < 16; ++nt) {
            const int Nb = nt * 64;
            {   // stage W tile
                const float* wsrc = w_ih + ((size_t)(Nb + wr)) * NIN + wk;
                #pragma unroll
                for (int j = 0; j < 4; ++j) {
                    float4 p0 = *(const float4*)(wsrc + 8 * j);
                    float4 p1 = *(const float4*)(wsrc + 8 * j + 4);
                    s16x8 tv;
                    tv[0] = f2bf(p0.x); tv[1] = f2bf(p0.y); tv[2] = f2bf(p0.z); tv[3] = f2bf(p0.w);
                    tv[4] = f2bf(p1.x); tv[5] = f2bf(p1.y); tv[6] = f2bf(p1.z); tv[7] = f2bf(p1.w);
                    *(s16x8*)&wl[wr][wk + 8 * j] = tv;
                }
            }
            __syncthreads();                                  // A
            f32x4 acc[4];
            #pragma unroll
            for (int nf = 0; nf < 4; ++nf) {
                const float bs = biasS[Nb + nf * 16 + lb];
                acc[nf][0] = bs; acc[nf][1] = bs; acc[nf][2] = bs; acc[nf][3] = bs;
            }
            #pragma unroll
            for (int kk = 0; kk < 4; ++kk)
                #pragma unroll
                for (int nf = 0; nf < 4; ++nf) {
                    s16x8 bf_ = *(const s16x8*)&wl[nf * 16 + lb][kk * 32 + 8 * lg];
                    acc[nf] = __builtin_amdgcn_mfma_f32_16x16x32_bf16(a[kk], bf_, acc[nf], 0, 0, 0);
                }
            // acc -> xo (bf16) for coalesced IC stores
            #pragma unroll
            for (int nf = 0; nf < 4; ++nf)
                #pragma unroll
                for (int rr = 0; rr < 4; ++rr)
                    xo[16 * v + 4 * lg + rr][nf * 16 + lb] = f2bf(acc[nf][rr]);
            __syncthreads();                                  // B
            {
                s16x8 v0 = *(const s16x8*)&xo[orow][oko];
                s16x8 v1 = *(const s16x8*)&xo[orow][oko + 8];
                unsigned short* dst = xp + ((size_t)(d * T_SEQ + t) * NB + b0 + orow) * 1024
                                         + Nb + oko;
                union { s16x8 s; i32x4 i; } u0, u1; u0.s = v0; u1.s = v1;
                asm volatile("global_store_dwordx4 %0, %1, off sc0 sc1"
                             :: "v"(dst), "v"(u0.i) : "memory");
                asm volatile("global_store_dwordx4 %0, %1, off sc0 sc1"
                             :: "v"(dst + 8), "v"(u1.i) : "memory");
            }
        }
        __syncthreads();   // vmcnt(0) per wave: all sc0sc1 stores ack'd at IC
        if (tid == 0) {
            int* fp = flags + (d * T_SEQ + t) * 4 + g;
            unsigned one = 1;
            asm volatile("global_store_dword %0, %1, off sc0 sc1"
                         :: "v"(fp), "v"(one) : "memory");
        }
        return;
    }

    // ================= rec role (R13 structure) =================
    const int d  = bid >> 6;
    const int bt = bid & 63;
    const float* w_hh = d ? w_hh_b : w_hh_f;
    const int w = tid >> 6, l = tid & 63, lg = l >> 4, lb = l & 15;
    const int c = l & 3, huq = l >> 2;

    int* hl = (int*)smem;                                    // 8 KB
    int (*rscr)[4][4][16] = (int(*)[4][4][16])(smem + 8192); // 16 KB

    i32x4 wq[4][4];
    #pragma unroll
    for (int G = 0; G < 4; ++G) {
        const int row = G * 256 + 16 * w + lb;
        #pragma unroll
        for (int kk = 0; kk < 4; ++kk) {
            i32x4 pk;
            #pragma unroll
            for (int r = 0; r < 4; ++r) {
                float4 wv = *(const float4*)(w_hh + (size_t)row * NH + kk * 64 + 16 * lg + 4 * r);
                const int q0 = (int)rintf(wv.x * 2032.0f) & 255;
                const int q1 = (int)rintf(wv.y * 2032.0f) & 255;
                const int q2 = (int)rintf(wv.z * 2032.0f) & 255;
                const int q3 = (int)rintf(wv.w * 2032.0f) & 255;
                pk[r] = q0 | (q1 << 8) | (q2 << 16) | (q3 << 24);
            }
            wq[G][kk] = pk;
        }
    }
    for (int i = tid; i < 2048; i += 1024) hl[i] = 0;

    const int hu = 16 * w + huq;
    const int hwb = (hu >> 6) * 1024 + ((hu >> 4) & 3) * 256 + c * 16 + (hu & 15);

    float cst = 0.f;
    unsigned short XPA[4], XPB[4];
    const int t0 = d ? (T_SEQ - 1) : 0;
    const long dxp  = (d ? -(long)NB : (long)NB) * 1024;
    const long dout = (d ? -(long)NB : (long)NB) * 512;
    const unsigned short* xpp =
        xp + ((size_t)(d * T_SEQ + t0) * NB + bt * 4 + c) * 1024 + hu;
    float* outp = out + ((size_t)t0 * NB + bt * 4 + c) * 512 + d * 256 + hu;

    // chunk wait: flags for steps s..min(s+32,187) of this WG's stream
    const int fgrp = bt >> 4;
    #define CHUNK_WAIT(S)                                                          \
    do {                                                                           \
        if (tid == 0) {                                                            \
            int ulim = (S) + 32; if (ulim > T_SEQ - 1) ulim = T_SEQ - 1;           \
            for (int u = (S); u <= ulim; ++u) {                                    \
                const int tt = d ? (T_SEQ - 1 - u) : u;                            \
                const int* fp = flags + (d * T_SEQ + tt) * 4 + fgrp;               \
                unsigned fv;                                                       \
                while (true) {                                                     \
                    asm volatile("global_load_dword %0, %1, off sc0 sc1\n\t"       \
                                 "s_waitcnt vmcnt(0)"                              \
                                 : "=v"(fv) : "v"(fp) : "memory");                 \
                    if (fv) break;                                                 \
                    __builtin_amdgcn_s_sleep(16);                                  \
                }                                                                  \
            }                                                                      \
            __builtin_amdgcn_fence(__ATOMIC_ACQUIRE, "agent");                     \
        }                                                                          \
        lds_barrier();                                                             \
    } while (0)

    CHUNK_WAIT(0);
    #pragma unroll
    for (int G = 0; G < 4; ++G)
        XPA[G] = xpp[G * 256];
    xpp += dxp;
    __syncthreads();

    for (int s2 = 0; s2 < T_SEQ / 2; ++s2) {
        if ((s2 & 15) == 0 && s2)
            CHUNK_WAIT(2 * s2);
        lstm_step(0, w, l, lg, lb, c, huq, hwb, xpp, dxp, outp, dout,
                  hl, rscr, wq, cst, XPA, XPB);
        lstm_step(1, w, l, lg, lb, c, huq, hwb, xpp, dxp, outp, dout,
                  hl, rscr, wq, cst, XPB, XPA);
    }
    #undef CHUNK_WAIT
}

// ================= Fallback (R3, 829 us): used only if ws too small ================
#define ZSTR_FB 392
__global__ __launch_bounds__(512, 2) void lstm_fb(
    const float* __restrict__ x,
    const float* __restrict__ w_ih_f, const float* __restrict__ w_hh_f,
    const float* __restrict__ b_ih_f, const float* __restrict__ b_hh_f,
    const float* __restrict__ w_ih_b, const float* __restrict__ w_hh_b,
    const float* __restrict__ b_ih_b, const float* __restrict__ b_hh_b,
    float* __restrict__ out, unsigned* __restrict__ flags)
{
    const int b  = blockIdx.x;
    const int d  = b >> 5;
    const int hh = (b >> 4) & 1;
    const int bt = b & 15;
    const int pb = b ^ 16;
    const int po = 1 - hh;
    const float* w_ih = d ? w_ih_b : w_ih_f;
    const float* w_hh = d ? w_hh_b : w_hh_f;
    const float* b_ih = d ? b_ih_b : b_ih_f;
    const float* b_hh = d ? b_hh_b : b_hh_f;
    const int tid = threadIdx.x;
    const int w = tid >> 6, l = tid & 63, lg = l >> 4, lb = l & 15;
    const int hbase = hh * 128 + 16 * w;

    __shared__ short Z[2][16][ZSTR_FB];
    __shared__ float biasL[8][4][16];
    const int off_x   = lg * 8;
    const int off_own = (4 + 4 * hh) * 32 + lg * 8;
    const int off_par = (4 + 4 * po) * 32 + lg * 8;

    s16x8 wf[4][12];
    #pragma unroll
    for (int G = 0; G < 4; ++G) {
        const int gc = G * 256 + hbase + lb;
        #pragma unroll
        for (int kkidx = 0; kkidx < 12; ++kkidx) {
            const int kb = (kkidx < 4) ? (off_x + 32 * kkidx)
                         : (kkidx < 8) ? (off_own + 32 * (kkidx - 4))
                                       : (off_par + 32 * (kkidx - 8));
            const float* src = (kb < NIN) ? (w_ih + (size_t)gc * NIN + kb)
                                          : (w_hh + (size_t)gc * NH + (kb - NIN));
            float4 a  = *(const float4*)(src);
            float4 b2 = *(const float4*)(src + 4);
            s16x8 tv;
            tv[0] = f2bf(a.x);  tv[1] = f2bf(a.y);  tv[2] = f2bf(a.z);  tv[3] = f2bf(a.w);
            tv[4] = f2bf(b2.x); tv[5] = f2bf(b2.y); tv[6] = f2bf(b2.z); tv[7] = f2bf(b2.w);
            wf[G][kkidx] = tv;
        }
    }
    {
        const int G = lb >> 2, r = lb & 3;
        const int gcr = G * 256 + hbase + 4 * lg + r;
        biasL[w][G][4 * lg + r] = b_ih[gcr] + b_hh[gcr];
    }
    const int srow = tid >> 5;
    const int sk4  = (tid & 31) * 4;
    {
        s16x8 zz;
        #pragma unroll
        for (int i = 0; i < 8; ++i) zz[i] = 0;
        *(s16x8*)&Z[0][srow][NIN + (tid & 31) * 8] = zz;
        const int t0 = d ? (T_SEQ - 1) : 0;
        float4 xv0 = *(const float4*)(x + ((size_t)(t0 * NB + bt * 16 + srow)) * NIN + sk4);
        s16x4 xp_;
        xp_[0] = f2bf(xv0.x); xp_[1] = f2bf(xv0.y); xp_[2] = f2bf(xv0.z); xp_[3] = f2bf(xv0.w);
        *(s16x4*)&Z[0][srow][sk4] = xp_;
    }
    float cst[4] = {0.f, 0.f, 0.f, 0.f};
    __syncthreads();
    unsigned* myflag = flags + b * 16;
    unsigned* pflag  = flags + pb * 16;
    float* outp = out + (size_t)(bt * 16) * 512 + d * 256 + hbase + 4 * lg;

    for (int s = 0; s < T_SEQ; ++s) {
        const int p = s & 1;
        const int t = d ? (T_SEQ - 1 - s) : s;
        float4 xv;
        const bool havex = (s + 1 < T_SEQ);
        if (havex) {
            const int tn = d ? (T_SEQ - 2 - s) : (s + 1);
            xv = *(const float4*)(x + ((size_t)(tn * NB + bt * 16 + srow)) * NIN + sk4);
        }
        f32x4 acc[4];
        #pragma unroll
        for (int G = 0; G < 4; ++G)
            acc[G] = *(const f32x4*)&biasL[w][G][4 * lg];
        const short* zrow = &Z[p][lb][0];
        #pragma unroll
        for (int kk = 0; kk < 4; ++kk) {
            s16x8 bfv = *(const s16x8*)(zrow + off_x + 32 * kk);
            acc[0] = __builtin_amdgcn_mfma_f32_16x16x32_bf16(wf[0][kk], bfv, acc[0], 0, 0, 0);
            acc[1] = __builtin_amdgcn_mfma_f32_16x16x32_bf16(wf[1][kk], bfv, acc[1], 0, 0, 0);
            acc[2] = __builtin_amdgcn_mfma_f32_16x16x32_bf16(wf[2][kk], bfv, acc[2], 0, 0, 0);
            acc[3] = __builtin_amdgcn_mfma_f32_16x16x32_bf16(wf[3][kk], bfv, acc[3], 0, 0, 0);
        }
        #pragma unroll
        for (int kk = 0; kk < 4; ++kk) {
            s16x8 bfv = *(const s16x8*)(zrow + off_own + 32 * kk);
            acc[0] = __builtin_amdgcn_mfma_f32_16x16x32_bf16(wf[0][4 + kk], bfv, acc[0], 0, 0, 0);
            acc[1] = __builtin_amdgcn_mfma_f32_16x16x32_bf16(wf[1][4 + kk], bfv, acc[1], 0, 0, 0);
            acc[2] = __builtin_amdgcn_mfma_f32_16x16x32_bf16(wf[2][4 + kk], bfv, acc[2], 0, 0, 0);
            acc[3] = __builtin_amdgcn_mfma_f32_16x16x32_bf16(wf[3][4 + kk], bfv, acc[3], 0, 0, 0);
        }
        if (s > 0) {
            const unsigned want = (unsigned)s;
            while (__hip_atomic_load(pflag, __ATOMIC_RELAXED, __HIP_MEMORY_SCOPE_AGENT) < want)
                __builtin_amdgcn_s_sleep(1);
            __builtin_amdgcn_fence(__ATOMIC_ACQUIRE, "agent");
            const int tprev = d ? (T_SEQ - s) : (s - 1);
            float4 pv = *(const float4*)(out + (size_t)tprev * NB * 512
                         + (size_t)(bt * 16 + srow) * 512 + d * 256 + po * 128 + sk4);
            s16x4 pp;
            pp[0] = f2bf(pv.x); pp[1] = f2bf(pv.y); pp[2] = f2bf(pv.z); pp[3] = f2bf(pv.w);
            *(s16x4*)&Z[p][srow][NIN + po * 128 + sk4] = pp;
        }
        __syncthreads();
        #pragma unroll
        for (int kk = 0; kk < 4; ++kk) {
            s16x8 bfv = *(const s16x8*)(zrow + off_par + 32 * kk);
            acc[0] = __builtin_amdgcn_mfma_f32_16x16x32_bf16(wf[0][8 + kk], bfv, acc[0], 0, 0, 0);
            acc[1] = __builtin_amdgcn_mfma_f32_16x16x32_bf16(wf[1][8 + kk], bfv, acc[1], 0, 0, 0);
            acc[2] = __builtin_amdgcn_mfma_f32_16x16x32_bf16(wf[2][8 + kk], bfv, acc[2], 0, 0, 0);
            acc[3] = __builtin_amdgcn_mfma_f32_16x16x32_bf16(wf[3][8 + kk], bfv, acc[3], 0, 0, 0);
        }
        float4 hout; s16x4 hbf;
        #pragma unroll
        for (int r = 0; r < 4; ++r) {
            const float iv = sigf(acc[0][r]);
            const float fv = sigf(acc[1][r]);
            const float gv = tanh_(acc[2][r]);
            const float ov = sigf(acc[3][r]);
            const float cc = fv * cst[r] + iv * gv;
            cst[r] = cc;
            const float h = ov * tanh_(cc);
            (&hout.x)[r] = h;
            hbf[r] = f2bf(h);
        }
        *(s16x4*)&Z[p ^ 1][lb][NIN + hbase + 4 * lg] = hbf;
        if (havex) {
            s16x4 xp_;
            xp_[0] = f2bf(xv.x); xp_[1] = f2bf(xv.y); xp_[2] = f2bf(xv.z); xp_[3] = f2bf(xv.w);
            *(s16x4*)&Z[p ^ 1][srow][sk4] = xp_;
        }
        *(f32x4*)(outp + (size_t)t * NB * 512 + lb * 512) = *(f32x4*)&hout;
        __syncthreads();
        if (tid == 0 && s + 1 < T_SEQ)
            __hip_atomic_store(myflag, (unsigned)(s + 1),
                               __ATOMIC_RELEASE, __HIP_MEMORY_SCOPE_AGENT);
    }
}

extern "C" void kernel_launch(void* const* d_in, const int* in_sizes, int n_in,
                              void* d_out, int out_size, void* d_ws, size_t ws_size,
                              hipStream_t stream) {
    const float* x      = (const float*)d_in[0];
    const float* w_ih_f = (const float*)d_in[1];
    const float* w_hh_f = (const float*)d_in[2];
    const float* b_ih_f = (const float*)d_in[3];
    const float* b_hh_f = (const float*)d_in[4];
    const float* w_ih_b = (const float*)d_in[5];
    const float* w_hh_b = (const float*)d_in[6];
    const float* b_ih_b = (const float*)d_in[7];
    const float* b_hh_b = (const float*)d_in[8];
    float* out = (float*)d_out;

    const size_t XPB = (size_t)2 * T_SEQ * NB * 1024 * 2;   // xp bytes (bf16)

    if (ws_size >= XPB + 8192) {
        unsigned short* xp = (unsigned short*)d_ws;
        int* flags = (int*)((char*)d_ws + XPB);
        hipMemsetAsync(flags, 0, 2 * T_SEQ * 4 * sizeof(int), stream);
        lstm_fused<<<dim3(NREC + 1504), dim3(1024), 0, stream>>>(
            x, w_ih_f, w_hh_f, b_ih_f, b_hh_f, w_ih_b, w_hh_b, b_ih_b, b_hh_b,
            xp, flags, out);
    } else {
        unsigned* flags = (unsigned*)d_ws;
        hipMemsetAsync(flags, 0, 4096, stream);
        lstm_fb<<<dim3(64), dim3(512), 0, stream>>>(
            x, w_ih_f, w_hh_f, b_ih_f, b_hh_f, w_ih_b, w_hh_b, b_ih_b, b_hh_b,
            out, flags);
    }
}

// Round 19
// 286.846 us; speedup vs baseline: 1.8207x; 1.8207x over previous
//
#include <hip/hip_runtime.h>

#define T_SEQ 188
#define NB    256
#define NIN   128
#define NH    256
#define SCQ   (0.0625f / 16129.0f)   // (0.0625/127) * (1/127)

typedef __attribute__((ext_vector_type(8))) short s16x8;
typedef __attribute__((ext_vector_type(4))) short s16x4;
typedef __attribute__((ext_vector_type(4))) float f32x4;
typedef __attribute__((ext_vector_type(4))) int   i32x4;

__device__ __forceinline__ short f2bf(float f) {
    union { float f; unsigned u; } v; v.f = f;
    unsigned r = v.u + 0x7fffu + ((v.u >> 16) & 1u);   // RNE
    return (short)(r >> 16);
}
__device__ __forceinline__ float bf2f(unsigned short s) {
    union { unsigned u; float f; } t; t.u = ((unsigned)s) << 16; return t.f;
}
__device__ __forceinline__ float sigf(float x) {
    return __builtin_amdgcn_rcpf(1.0f + __expf(-x));
}
__device__ __forceinline__ float tanh_(float x) {
    return 1.0f - 2.0f * __builtin_amdgcn_rcpf(__expf(2.0f * x) + 1.0f);
}
__device__ __forceinline__ void lds_barrier() {
    asm volatile("s_waitcnt lgkmcnt(0)" ::: "memory");
    __builtin_amdgcn_s_barrier();
    asm volatile("" ::: "memory");
}

// ===== Pre-pass: W_ih (both dirs) -> bf16, swizzled to MFMA B-fragment order ======
// Chunk j (s16x8, 8 shorts) for (d, nt, q=nf*4+kk, lane l):
//   gate = nt*64 + nf*16 + (l&15),  k = kk*32 + 8*(l>>4) + e.
// Chunk index j = d*16384 + nt*1024 + q*64 + l; short offset = j*8.
// Per-direction stride = 131072 shorts; per-tile stride = 8192 shorts.
__global__ __launch_bounds__(256) void wconv(
    const float* __restrict__ w_ih_f, const float* __restrict__ w_ih_b,
    unsigned short* __restrict__ wswz)
{
    const int j = blockIdx.x * 256 + threadIdx.x;
    const int d  = j >> 14;
    const int r  = j & 16383;
    const int nt = r >> 10;
    const int rr = r & 1023;
    const int q  = rr >> 6;
    const int l  = rr & 63;
    const int nf = q >> 2, kk = q & 3;
    const int gate = nt * 64 + nf * 16 + (l & 15);
    const int kb   = kk * 32 + 8 * (l >> 4);
    const float* src = (d ? w_ih_b : w_ih_f) + (size_t)gate * NIN + kb;
    float4 p0 = *(const float4*)(src);
    float4 p1 = *(const float4*)(src + 4);
    s16x8 tv;
    tv[0] = f2bf(p0.x); tv[1] = f2bf(p0.y); tv[2] = f2bf(p0.z); tv[3] = f2bf(p0.w);
    tv[4] = f2bf(p1.x); tv[5] = f2bf(p1.y); tv[6] = f2bf(p1.z); tv[7] = f2bf(p1.w);
    *(s16x8*)(wswz + (size_t)j * 8) = tv;
}

// ===== Phase 1: xp = x·W_ih^T + biases (bf16 out) =================================
// One WG = M=64 rows x full N=1024. x A-frags in registers (once). W streams
// from the pre-swizzled bf16 buffer through a DOUBLE-BUFFERED LDS tile
// (coalesced copy; loads for tile nt+1 issued before tile nt's MFMAs).
// Output goes through an LDS transpose (xo) -> 2 coalesced dwordx4 stores.
__global__ __launch_bounds__(256) void xp_gemm(
    const float* __restrict__ x, const unsigned short* __restrict__ wswz,
    const float* __restrict__ b_ih_f, const float* __restrict__ b_hh_f,
    const float* __restrict__ b_ih_b, const float* __restrict__ b_hh_b,
    unsigned short* __restrict__ xp)
{
    const int mt = blockIdx.x >> 1;
    const int d  = blockIdx.x & 1;
    const int t  = mt >> 2, b0 = (mt & 3) * 64;
    const float* b_ih = d ? b_ih_b : b_ih_f;
    const float* b_hh = d ? b_hh_b : b_hh_f;
    const int tid = threadIdx.x;
    const int v = tid >> 6, l = tid & 63, lg = l >> 4, lb = l & 15;

    __shared__ short wl[2][8192];     // 2 x 16 KB W tiles, fragment-linear
    __shared__ short xo[64][68];      // output transpose buffer
    __shared__ float biasS[1024];

    {
        const int g4 = tid * 4;
        float4 bi = *(const float4*)(b_ih + g4);
        float4 bh = *(const float4*)(b_hh + g4);
        biasS[g4 + 0] = bi.x + bh.x; biasS[g4 + 1] = bi.y + bh.y;
        biasS[g4 + 2] = bi.z + bh.z; biasS[g4 + 3] = bi.w + bh.w;
    }

    // x A-fragments -> registers (once): lane holds A[16v+lb][32kk+8lg+e]
    s16x8 a[4];
    {
        const float* xr = x + ((size_t)(t * NB + b0 + 16 * v + lb)) * NIN + 8 * lg;
        #pragma unroll
        for (int kk = 0; kk < 4; ++kk) {
            float4 p0 = *(const float4*)(xr + 32 * kk);
            float4 p1 = *(const float4*)(xr + 32 * kk + 4);
            s16x8 tv;
            tv[0] = f2bf(p0.x); tv[1] = f2bf(p0.y); tv[2] = f2bf(p0.z); tv[3] = f2bf(p0.w);
            tv[4] = f2bf(p1.x); tv[5] = f2bf(p1.y); tv[6] = f2bf(p1.z); tv[7] = f2bf(p1.w);
            a[kk] = tv;
        }
    }

    const unsigned short* wbase = wswz + (size_t)d * 131072;   // FIX: short units
    s16x8 stg[4];
    // prologue: tile 0 -> wl[0]  (chunk c = tid + 256*i: linear, conflict-free)
    #pragma unroll
    for (int i = 0; i < 4; ++i)
        stg[i] = *(const s16x8*)(wbase + ((size_t)(tid + 256 * i)) * 8);
    #pragma unroll
    for (int i = 0; i < 4; ++i)
        *(s16x8*)&wl[0][(tid + 256 * i) * 8] = stg[i];
    __syncthreads();

    unsigned short* xrow =
        xp + ((size_t)(d * T_SEQ + t) * NB + b0 + (tid >> 2)) * 1024 + (tid & 3) * 16;

    for (int nt = 0; nt < 16; ++nt) {
        const int cur = nt & 1;
        // [A] issue next W tile loads (latency hides under MFMA + store phase)
        if (nt + 1 < 16) {
            #pragma unroll
            for (int i = 0; i < 4; ++i)
                stg[i] = *(const s16x8*)(wbase + ((size_t)(nt + 1) * 8192)   // FIX
                                               + ((size_t)(tid + 256 * i)) * 8);
        }
        // [B] MFMAs: 4 N-frags x 4 K-tiles from wl[cur]
        f32x4 acc[4];
        #pragma unroll
        for (int nf = 0; nf < 4; ++nf) {
            const float bs = biasS[nt * 64 + nf * 16 + lb];
            acc[nf][0] = bs; acc[nf][1] = bs; acc[nf][2] = bs; acc[nf][3] = bs;
        }
        #pragma unroll
        for (int kk = 0; kk < 4; ++kk)
            #pragma unroll
            for (int nf = 0; nf < 4; ++nf) {
                s16x8 bf_ = *(const s16x8*)&wl[cur][((nf * 4 + kk) * 64 + l) * 8];
                acc[nf] = __builtin_amdgcn_mfma_f32_16x16x32_bf16(a[kk], bf_, acc[nf], 0, 0, 0);
            }
        // acc -> xo (transpose for coalesced stores)
        #pragma unroll
        for (int nf = 0; nf < 4; ++nf)
            #pragma unroll
            for (int rr = 0; rr < 4; ++rr)
                xo[16 * v + 4 * lg + rr][nf * 16 + lb] = f2bf(acc[nf][rr]);
        lds_barrier();
        // [C] coalesced xp stores: row tid>>2, 32B per thread (2 dwordx4)
        {
            s16x8 o0 = *(const s16x8*)&xo[tid >> 2][(tid & 3) * 16];
            s16x8 o1 = *(const s16x8*)&xo[tid >> 2][(tid & 3) * 16 + 8];
            *(s16x8*)(xrow + nt * 64)     = o0;
            *(s16x8*)(xrow + nt * 64 + 8) = o1;
        }
        // [D] commit staged W to the other buffer; barrier
        if (nt + 1 < 16) {
            #pragma unroll
            for (int i = 0; i < 4; ++i)
                *(s16x8*)&wl[cur ^ 1][(tid + 256 * i) * 8] = stg[i];
        }
        lds_barrier();
    }
}

// ================= Phase 2: recurrence (R13/R16 structure, proven 237 us) =========
__device__ __forceinline__ void lstm_step(
    int p, int w, int l, int lg, int lb, int c, int huq, int hwb,
    const unsigned short*& xpp, long dxp, float*& outp, long dout,
    int* hl, int (&rscr)[16][4][4][16],
    const i32x4 (&wq)[4][4], float& cst,
    unsigned short (&cur)[4], unsigned short (&nxt)[4])
{
    #pragma unroll
    for (int G = 0; G < 4; ++G)
        nxt[G] = xpp[G * 256];
    xpp += dxp;

    i32x4 ac[4];
    #pragma unroll
    for (int G = 0; G < 4; ++G) {
        ac[G][0] = 0; ac[G][1] = 0; ac[G][2] = 0; ac[G][3] = 0;
    }
    #pragma unroll
    for (int kk = 0; kk < 4; ++kk) {
        i32x4 bq = *(const i32x4*)&hl[p * 1024 + kk * 256 + 4 * l];
        ac[0] = __builtin_amdgcn_mfma_i32_16x16x64_i8(wq[0][kk], bq, ac[0], 0, 0, 0);
        ac[1] = __builtin_amdgcn_mfma_i32_16x16x64_i8(wq[1][kk], bq, ac[1], 0, 0, 0);
        ac[2] = __builtin_amdgcn_mfma_i32_16x16x64_i8(wq[2][kk], bq, ac[2], 0, 0, 0);
        ac[3] = __builtin_amdgcn_mfma_i32_16x16x64_i8(wq[3][kk], bq, ac[3], 0, 0, 0);
    }

    if (lb < 4) {
        #pragma unroll
        for (int G = 0; G < 4; ++G)
            *(i32x4*)&rscr[w][G][lb][4 * lg] = ac[G];
    }
    asm volatile("s_waitcnt lgkmcnt(0)" ::: "memory");
    int av[4];
    #pragma unroll
    for (int G = 0; G < 4; ++G)
        av[G] = rscr[w][G][c][huq];
    asm volatile("s_waitcnt lgkmcnt(0)" ::: "memory");

    const float gi = SCQ * (float)av[0] + bf2f(cur[0]);
    const float gf = SCQ * (float)av[1] + bf2f(cur[1]);
    const float gg = SCQ * (float)av[2] + bf2f(cur[2]);
    const float go = SCQ * (float)av[3] + bf2f(cur[3]);
    const float iv = sigf(gi), fv = sigf(gf);
    const float gv = tanh_(gg), ov = sigf(go);
    const float cc = fv * cst + iv * gv;
    cst = cc;
    const float h = ov * tanh_(cc);
    *outp = h;
    outp += dout;
    ((signed char*)hl)[(p ^ 1) * 4096 + hwb] = (signed char)(int)rintf(h * 127.0f);

    lds_barrier();
}

__global__ __launch_bounds__(1024, 4) void lstm_rec(
    const float* __restrict__ w_hh_f, const float* __restrict__ w_hh_b,
    const unsigned short* __restrict__ xp, float* __restrict__ out)
{
    const int bid = blockIdx.x;
    const int d  = bid >> 6;
    const int bt = bid & 63;
    const float* w_hh = d ? w_hh_b : w_hh_f;
    const int tid = threadIdx.x;
    const int w = tid >> 6, l = tid & 63, lg = l >> 4, lb = l & 15;
    const int c = l & 3, huq = l >> 2;

    __shared__ int hl[2 * 1024];         // i8 h, linear-read layout (8 KB)
    __shared__ int rscr[16][4][4][16];   // [wave][gate][col][hu] - wave-private

    i32x4 wq[4][4];
    #pragma unroll
    for (int G = 0; G < 4; ++G) {
        const int row = G * 256 + 16 * w + lb;
        #pragma unroll
        for (int kk = 0; kk < 4; ++kk) {
            i32x4 pk;
            #pragma unroll
            for (int r = 0; r < 4; ++r) {
                float4 wv = *(const float4*)(w_hh + (size_t)row * NH + kk * 64 + 16 * lg + 4 * r);
                const int q0 = (int)rintf(wv.x * 2032.0f) & 255;
                const int q1 = (int)rintf(wv.y * 2032.0f) & 255;
                const int q2 = (int)rintf(wv.z * 2032.0f) & 255;
                const int q3 = (int)rintf(wv.w * 2032.0f) & 255;
                pk[r] = q0 | (q1 << 8) | (q2 << 16) | (q3 << 24);
            }
            wq[G][kk] = pk;
        }
    }
    for (int i = tid; i < 2048; i += 1024) hl[i] = 0;   // h(0) = 0, both buffers

    const int hu = 16 * w + huq;
    const int hwb = (hu >> 6) * 1024 + ((hu >> 4) & 3) * 256 + c * 16 + (hu & 15);

    float cst = 0.f;
    unsigned short XPA[4], XPB[4];
    const int t0 = d ? (T_SEQ - 1) : 0;
    const long dxp  = (d ? -(long)NB : (long)NB) * 1024;
    const long dout = (d ? -(long)NB : (long)NB) * 512;
    const unsigned short* xpp =
        xp + ((size_t)(d * T_SEQ + t0) * NB + bt * 4 + c) * 1024 + hu;
    float* outp = out + ((size_t)t0 * NB + bt * 4 + c) * 512 + d * 256 + hu;
    #pragma unroll
    for (int G = 0; G < 4; ++G)
        XPA[G] = xpp[G * 256];
    xpp += dxp;
    __syncthreads();

    for (int s2 = 0; s2 < T_SEQ / 2; ++s2) {
        lstm_step(0, w, l, lg, lb, c, huq, hwb, xpp, dxp, outp, dout,
                  hl, rscr, wq, cst, XPA, XPB);
        lstm_step(1, w, l, lg, lb, c, huq, hwb, xpp, dxp, outp, dout,
                  hl, rscr, wq, cst, XPB, XPA);
    }
}

// ================= Fallback (R3, 829 us): used only if ws too small ================
#define ZSTR_FB 392
__global__ __launch_bounds__(512, 2) void lstm_fb(
    const float* __restrict__ x,
    const float* __restrict__ w_ih_f, const float* __restrict__ w_hh_f,
    const float* __restrict__ b_ih_f, const float* __restrict__ b_hh_f,
    const float* __restrict__ w_ih_b, const float* __restrict__ w_hh_b,
    const float* __restrict__ b_ih_b, const float* __restrict__ b_hh_b,
    float* __restrict__ out, unsigned* __restrict__ flags)
{
    const int b  = blockIdx.x;
    const int d  = b >> 5;
    const int hh = (b >> 4) & 1;
    const int bt = b & 15;
    const int pb = b ^ 16;
    const int po = 1 - hh;
    const float* w_ih = d ? w_ih_b : w_ih_f;
    const float* w_hh = d ? w_hh_b : w_hh_f;
    const float* b_ih = d ? b_ih_b : b_ih_f;
    const float* b_hh = d ? b_hh_b : b_hh_f;
    const int tid = threadIdx.x;
    const int w = tid >> 6, l = tid & 63, lg = l >> 4, lb = l & 15;
    const int hbase = hh * 128 + 16 * w;

    __shared__ short Z[2][16][ZSTR_FB];
    __shared__ float biasL[8][4][16];
    const int off_x   = lg * 8;
    const int off_own = (4 + 4 * hh) * 32 + lg * 8;
    const int off_par = (4 + 4 * po) * 32 + lg * 8;

    s16x8 wf[4][12];
    #pragma unroll
    for (int G = 0; G < 4; ++G) {
        const int gc = G * 256 + hbase + lb;
        #pragma unroll
        for (int kkidx = 0; kkidx < 12; ++kkidx) {
            const int kb = (kkidx < 4) ? (off_x + 32 * kkidx)
                         : (kkidx < 8) ? (off_own + 32 * (kkidx - 4))
                                       : (off_par + 32 * (kkidx - 8));
            const float* src = (kb < NIN) ? (w_ih + (size_t)gc * NIN + kb)
                                          : (w_hh + (size_t)gc * NH + (kb - NIN));
            float4 a  = *(const float4*)(src);
            float4 b2 = *(const float4*)(src + 4);
            s16x8 tv;
            tv[0] = f2bf(a.x);  tv[1] = f2bf(a.y);  tv[2] = f2bf(a.z);  tv[3] = f2bf(a.w);
            tv[4] = f2bf(b2.x); tv[5] = f2bf(b2.y); tv[6] = f2bf(b2.z); tv[7] = f2bf(b2.w);
            wf[G][kkidx] = tv;
        }
    }
    {
        const int G = lb >> 2, r = lb & 3;
        const int gcr = G * 256 + hbase + 4 * lg + r;
        biasL[w][G][4 * lg + r] = b_ih[gcr] + b_hh[gcr];
    }
    const int srow = tid >> 5;
    const int sk4  = (tid & 31) * 4;
    {
        s16x8 zz;
        #pragma unroll
        for (int i = 0; i < 8; ++i) zz[i] = 0;
        *(s16x8*)&Z[0][srow][NIN + (tid & 31) * 8] = zz;
        const int t0 = d ? (T_SEQ - 1) : 0;
        float4 xv0 = *(const float4*)(x + ((size_t)(t0 * NB + bt * 16 + srow)) * NIN + sk4);
        s16x4 xp_;
        xp_[0] = f2bf(xv0.x); xp_[1] = f2bf(xv0.y); xp_[2] = f2bf(xv0.z); xp_[3] = f2bf(xv0.w);
        *(s16x4*)&Z[0][srow][sk4] = xp_;
    }
    float cst[4] = {0.f, 0.f, 0.f, 0.f};
    __syncthreads();
    unsigned* myflag = flags + b * 16;
    unsigned* pflag  = flags + pb * 16;
    float* outp = out + (size_t)(bt * 16) * 512 + d * 256 + hbase + 4 * lg;

    for (int s = 0; s < T_SEQ; ++s) {
        const int p = s & 1;
        const int t = d ? (T_SEQ - 1 - s) : s;
        float4 xv;
        const bool havex = (s + 1 < T_SEQ);
        if (havex) {
            const int tn = d ? (T_SEQ - 2 - s) : (s + 1);
            xv = *(const float4*)(x + ((size_t)(tn * NB + bt * 16 + srow)) * NIN + sk4);
        }
        f32x4 acc[4];
        #pragma unroll
        for (int G = 0; G < 4; ++G)
            acc[G] = *(const f32x4*)&biasL[w][G][4 * lg];
        const short* zrow = &Z[p][lb][0];
        #pragma unroll
        for (int kk = 0; kk < 4; ++kk) {
            s16x8 bfv = *(const s16x8*)(zrow + off_x + 32 * kk);
            acc[0] = __builtin_amdgcn_mfma_f32_16x16x32_bf16(wf[0][kk], bfv, acc[0], 0, 0, 0);
            acc[1] = __builtin_amdgcn_mfma_f32_16x16x32_bf16(wf[1][kk], bfv, acc[1], 0, 0, 0);
            acc[2] = __builtin_amdgcn_mfma_f32_16x16x32_bf16(wf[2][kk], bfv, acc[2], 0, 0, 0);
            acc[3] = __builtin_amdgcn_mfma_f32_16x16x32_bf16(wf[3][kk], bfv, acc[3], 0, 0, 0);
        }
        #pragma unroll
        for (int kk = 0; kk < 4; ++kk) {
            s16x8 bfv = *(const s16x8*)(zrow + off_own + 32 * kk);
            acc[0] = __builtin_amdgcn_mfma_f32_16x16x32_bf16(wf[0][4 + kk], bfv, acc[0], 0, 0, 0);
            acc[1] = __builtin_amdgcn_mfma_f32_16x16x32_bf16(wf[1][4 + kk], bfv, acc[1], 0, 0, 0);
            acc[2] = __builtin_amdgcn_mfma_f32_16x16x32_bf16(wf[2][4 + kk], bfv, acc[2], 0, 0, 0);
            acc[3] = __builtin_amdgcn_mfma_f32_16x16x32_bf16(wf[3][4 + kk], bfv, acc[3], 0, 0, 0);
        }
        if (s > 0) {
            const unsigned want = (unsigned)s;
            while (__hip_atomic_load(pflag, __ATOMIC_RELAXED, __HIP_MEMORY_SCOPE_AGENT) < want)
                __builtin_amdgcn_s_sleep(1);
            __builtin_amdgcn_fence(__ATOMIC_ACQUIRE, "agent");
            const int tprev = d ? (T_SEQ - s) : (s - 1);
            float4 pv = *(const float4*)(out + (size_t)tprev * NB * 512
                         + (size_t)(bt * 16 + srow) * 512 + d * 256 + po * 128 + sk4);
            s16x4 pp;
            pp[0] = f2bf(pv.x); pp[1] = f2bf(pv.y); pp[2] = f2bf(pv.z); pp[3] = f2bf(pv.w);
            *(s16x4*)&Z[p][srow][NIN + po * 128 + sk4] = pp;
        }
        __syncthreads();
        #pragma unroll
        for (int kk = 0; kk < 4; ++kk) {
            s16x8 bfv = *(const s16x8*)(zrow + off_par + 32 * kk);
            acc[0] = __builtin_amdgcn_mfma_f32_16x16x32_bf16(wf[0][8 + kk], bfv, acc[0], 0, 0, 0);
            acc[1] = __builtin_amdgcn_mfma_f32_16x16x32_bf16(wf[1][8 + kk], bfv, acc[1], 0, 0, 0);
            acc[2] = __builtin_amdgcn_mfma_f32_16x16x32_bf16(wf[2][8 + kk], bfv, acc[2], 0, 0, 0);
            acc[3] = __builtin_amdgcn_mfma_f32_16x16x32_bf16(wf[3][8 + kk], bfv, acc[3], 0, 0, 0);
        }
        float4 hout; s16x4 hbf;
        #pragma unroll
        for (int r = 0; r < 4; ++r) {
            const float iv = sigf(acc[0][r]);
            const float fv = sigf(acc[1][r]);
            const float gv = tanh_(acc[2][r]);
            const float ov = sigf(acc[3][r]);
            const float cc = fv * cst[r] + iv * gv;
            cst[r] = cc;
            const float h = ov * tanh_(cc);
            (&hout.x)[r] = h;
            hbf[r] = f2bf(h);
        }
        *(s16x4*)&Z[p ^ 1][lb][NIN + hbase + 4 * lg] = hbf;
        if (havex) {
            s16x4 xp_;
            xp_[0] = f2bf(xv.x); xp_[1] = f2bf(xv.y); xp_[2] = f2bf(xv.z); xp_[3] = f2bf(xv.w);
            *(s16x4*)&Z[p ^ 1][srow][sk4] = xp_;
        }
        *(f32x4*)(outp + (size_t)t * NB * 512 + lb * 512) = *(f32x4*)&hout;
        __syncthreads();
        if (tid == 0 && s + 1 < T_SEQ)
            __hip_atomic_store(myflag, (unsigned)(s + 1),
                               __ATOMIC_RELEASE, __HIP_MEMORY_SCOPE_AGENT);
    }
}

extern "C" void kernel_launch(void* const* d_in, const int* in_sizes, int n_in,
                              void* d_out, int out_size, void* d_ws, size_t ws_size,
                              hipStream_t stream) {
    const float* x      = (const float*)d_in[0];
    const float* w_ih_f = (const float*)d_in[1];
    const float* w_hh_f = (const float*)d_in[2];
    const float* b_ih_f = (const float*)d_in[3];
    const float* b_hh_f = (const float*)d_in[4];
    const float* w_ih_b = (const float*)d_in[5];
    const float* w_hh_b = (const float*)d_in[6];
    const float* b_ih_b = (const float*)d_in[7];
    const float* b_hh_b = (const float*)d_in[8];
    float* out = (float*)d_out;

    const size_t XPB = (size_t)2 * T_SEQ * NB * 1024 * 2;   // xp bytes (bf16)
    const size_t WSW = (size_t)32768 * 16;                  // 512 KB swizzled W

    if (ws_size >= XPB + WSW) {
        unsigned short* xp   = (unsigned short*)d_ws;
        unsigned short* wswz = (unsigned short*)((char*)d_ws + XPB);
        wconv<<<dim3(128), dim3(256), 0, stream>>>(w_ih_f, w_ih_b, wswz);
        xp_gemm<<<dim3(752 * 2), dim3(256), 0, stream>>>(
            x, wswz, b_ih_f, b_hh_f, b_ih_b, b_hh_b, xp);
        lstm_rec<<<dim3(128), dim3(1024), 0, stream>>>(w_hh_f, w_hh_b, xp, out);
    } else {
        unsigned* flags = (unsigned*)d_ws;
        hipMemsetAsync(flags, 0, 4096, stream);
        lstm_fb<<<dim3(64), dim3(512), 0, stream>>>(
            x, w_ih_f, w_hh_f, b_ih_f, b_hh_f, w_ih_b, w_hh_b, b_ih_b, b_hh_b,
            out, flags);
    }
}